// Round 2
// baseline (581.352 us; speedup 1.0000x reference)
//
#include <hip/hip_runtime.h>

#define N_PTS 150000
#define NK 27
#define CIN 128
#define COUT 128

typedef __attribute__((ext_vector_type(8))) short bfrag8;   // 8 bf16 (4 VGPRs)
typedef __attribute__((ext_vector_type(4))) float facc4;    // 4 f32 accum

__device__ inline unsigned short f2bf(float f) {
    unsigned u = __builtin_bit_cast(unsigned, f);
    u += 0x7FFFu + ((u >> 16) & 1u);            // RNE
    return (unsigned short)(u >> 16);
}
__device__ inline unsigned pack2(float a, float b) {
    return (unsigned)f2bf(a) | ((unsigned)f2bf(b) << 16);
}

// barrier that does NOT drain vmcnt: LDS-visibility only, prefetch loads stay in flight
__device__ inline void block_sync_lds() {
    asm volatile("s_waitcnt lgkmcnt(0)" ::: "memory");
    __builtin_amdgcn_sched_barrier(0);
    __builtin_amdgcn_s_barrier();
    __builtin_amdgcn_sched_barrier(0);
    asm volatile("" ::: "memory");
}

// ---- prep: fp32 data -> bf16, plus one zeroed row at index N_PTS ----
__global__ void cast_data_kernel(const float* __restrict__ in,
                                 unsigned short* __restrict__ out) {
    const int n8_data = N_PTS * (CIN / 8);
    const int n8_all  = (N_PTS + 1) * (CIN / 8);
    int i = blockIdx.x * blockDim.x + threadIdx.x;
    int stride = gridDim.x * blockDim.x;
    for (; i < n8_all; i += stride) {
        uint4 v;
        if (i < n8_data) {
            const float4* p = (const float4*)(in + (size_t)i * 8);
            float4 x = p[0], y = p[1];
            v.x = pack2(x.x, x.y); v.y = pack2(x.z, x.w);
            v.z = pack2(y.x, y.y); v.w = pack2(y.z, y.w);
        } else {
            v.x = v.y = v.z = v.w = 0u;
        }
        *(uint4*)(out + (size_t)i * 8) = v;
    }
}

// ---- prep: W[co][k][ci] fp32 -> wk[k][co][ci] bf16 ----
__global__ void prep_weights_kernel(const float* __restrict__ w,
                                    unsigned short* __restrict__ wk, int total4) {
    int i = blockIdx.x * blockDim.x + threadIdx.x;
    if (i >= total4) return;
    int o = i * 4;
    int ci = o & 127;
    int co = (o >> 7) & 127;
    int k  = o >> 14;
    float4 x = *(const float4*)(w + ((size_t)co * NK + k) * CIN + ci);
    uint2 v;
    v.x = pack2(x.x, x.y); v.y = pack2(x.z, x.w);
    *(uint2*)(wk + o) = v;
}

// ---- main pipelined kernel: A gathered straight to registers, B via swizzled LDS ----
__global__ __launch_bounds__(256, 2)
void octconv_pipe(const unsigned short* __restrict__ dbf,   // [N_PTS+1][128] bf16 (last row zero)
                  const unsigned short* __restrict__ wk,    // [27][128][128] bf16
                  const int* __restrict__ nbr,
                  float* __restrict__ out) {
    __shared__ __align__(1024) unsigned char ldsB[COUT * CIN * 2];  // 32 KB, XOR-swizzled

    const int t  = threadIdx.x;
    const int w  = t >> 6;
    const int l  = t & 63;
    const int lr = l & 15;          // A row / B,D col within 16-tile
    const int lk = l >> 4;          // k-chunk
    const int m0 = blockIdx.x * 128;

    const int rowA = m0 + w * 32 + lr;
    const int rowB = rowA + 16;
    const bool vA = rowA < N_PTS;
    const bool vB = rowB < N_PTS;

    // B staging coords: thread -> (row tw, 64-elem half)
    const int tw   = t >> 1;
    const int half = t & 1;
    const int bswz = (tw & 7) << 4;

    facc4 acc0[8], acc1[8];
    const facc4 fz = {0.f, 0.f, 0.f, 0.f};
#pragma unroll
    for (int i = 0; i < 8; ++i) { acc0[i] = fz; acc1[i] = fz; }

    uint4 aC0[4], aC1[4], aN0[4], aN1[4];   // A frags: [kk], cur / next
    uint4 bC[8],  bN[8];                    // B staging regs: cur / next

    // ---- prologue: idx(0) -> issue B(0), A(0) -> issue idx(1) ----
    int ia_n = vA ? nbr[rowA * NK + 0] : -1;
    int ib_n = vB ? nbr[rowB * NK + 0] : -1;
    {
        const uint4* bs = (const uint4*)(wk + (size_t)tw * CIN + half * 64);
#pragma unroll
        for (int i = 0; i < 8; ++i) bC[i] = bs[i];
        int iaE = ia_n >= 0 ? ia_n : N_PTS;
        int ibE = ib_n >= 0 ? ib_n : N_PTS;
        const uint4* pa = (const uint4*)(dbf + (size_t)iaE * CIN + lk * 8);
        const uint4* pb = (const uint4*)(dbf + (size_t)ibE * CIN + lk * 8);
#pragma unroll
        for (int kk = 0; kk < 4; ++kk) { aC0[kk] = pa[kk * 4]; aC1[kk] = pb[kk * 4]; }
        ia_n = vA ? nbr[rowA * NK + 1] : -1;
        ib_n = vB ? nbr[rowB * NK + 1] : -1;
    }

    auto body = [&](uint4 (&ac0)[4], uint4 (&ac1)[4], uint4 (&an0)[4], uint4 (&an1)[4],
                    uint4 (&bc)[8], uint4 (&bn)[8], int k) {
        // stage B(k) regs -> LDS (swizzled)
#pragma unroll
        for (int i = 0; i < 8; ++i) {
            int off = (tw * 256 + half * 128 + i * 16) ^ bswz;
            *(uint4*)(ldsB + off) = bc[i];
        }
        block_sync_lds();
        if (k < NK - 1) {
            // issue B(k+1) first (drained first at next iter's ds_write)
            const uint4* bs = (const uint4*)(wk + (size_t)(k + 1) * (COUT * CIN) +
                                             (size_t)tw * CIN + half * 64);
#pragma unroll
            for (int i = 0; i < 8; ++i) bn[i] = bs[i];
            // gather A(k+1) straight to regs (zero-row trick for invalid idx)
            int iaE = ia_n >= 0 ? ia_n : N_PTS;
            int ibE = ib_n >= 0 ? ib_n : N_PTS;
            const uint4* pa = (const uint4*)(dbf + (size_t)iaE * CIN + lk * 8);
            const uint4* pb = (const uint4*)(dbf + (size_t)ibE * CIN + lk * 8);
#pragma unroll
            for (int kk = 0; kk < 4; ++kk) { an0[kk] = pa[kk * 4]; an1[kk] = pb[kk * 4]; }
            // issue idx(k+2)
            int k2 = (k + 2 < NK) ? k + 2 : NK - 1;
            ia_n = vA ? nbr[rowA * NK + k2] : -1;
            ib_n = vB ? nbr[rowB * NK + k2] : -1;
        }
        // MFMA over current tile
#pragma unroll
        for (int kk = 0; kk < 4; ++kk) {
            bfrag8 a0 = __builtin_bit_cast(bfrag8, ac0[kk]);
            bfrag8 a1 = __builtin_bit_cast(bfrag8, ac1[kk]);
#pragma unroll
            for (int ct = 0; ct < 8; ++ct) {
                int off = ((ct * 16 + lr) * 256 + kk * 64 + lk * 16) ^ ((lr & 7) << 4);
                bfrag8 b = *(const bfrag8*)(ldsB + off);
                acc0[ct] = __builtin_amdgcn_mfma_f32_16x16x32_bf16(a0, b, acc0[ct], 0, 0, 0);
                acc1[ct] = __builtin_amdgcn_mfma_f32_16x16x32_bf16(a1, b, acc1[ct], 0, 0, 0);
            }
        }
        block_sync_lds();
    };

    for (int k = 0; k < NK - 1; k += 2) {
        body(aC0, aC1, aN0, aN1, bC, bN, k);
        body(aN0, aN1, aC0, aC1, bN, bC, k + 1);
    }
    body(aC0, aC1, aN0, aN1, bC, bN, NK - 1);   // k = 26 (no prefetch)

    // ---- epilogue: C/D layout col=lane&15, row=(lane>>4)*4+reg ----
    const int rbase = m0 + w * 32 + lk * 4;
#pragma unroll
    for (int ct = 0; ct < 8; ++ct) {
#pragma unroll
        for (int r = 0; r < 4; ++r) {
            int row0 = rbase + r;
            if (row0 < N_PTS) out[(size_t)row0 * COUT + ct * 16 + lr] = acc0[ct][r];
            int row1 = row0 + 16;
            if (row1 < N_PTS) out[(size_t)row1 * COUT + ct * 16 + lr] = acc1[ct][r];
        }
    }
}

// ---- fallback (ws too small for bf16 data copy): fp32 gather, padded LDS ----
__global__ __launch_bounds__(256, 2)
void octconv_fp32(const float* __restrict__ data,
                  const unsigned short* __restrict__ wk,
                  const int* __restrict__ nbr,
                  float* __restrict__ out) {
    __shared__ unsigned short ldsA[128 * 136];
    __shared__ unsigned short ldsB[128 * 136];
    const int t = threadIdx.x, m0 = blockIdx.x * 128;
    const int w = t >> 6, l = t & 63, lr = l & 15, lk = l >> 4;
    const int ar = t >> 1, ac = (t & 1) * 64, m = m0 + ar;
    facc4 acc0[8], acc1[8];
    const facc4 fz = {0.f, 0.f, 0.f, 0.f};
#pragma unroll
    for (int i = 0; i < 8; ++i) { acc0[i] = fz; acc1[i] = fz; }
    const unsigned short* aP0 = &ldsA[(w * 32 + lr) * 136 + lk * 8];
    const unsigned short* aP1 = aP0 + 16 * 136;
    for (int k = 0; k < NK; ++k) {
        int idx = (m < N_PTS) ? nbr[m * NK + k] : -1;
        uint4* dst = (uint4*)&ldsA[ar * 136 + ac];
        if (idx >= 0) {
            const float4* src = (const float4*)(data + (size_t)idx * CIN + ac);
#pragma unroll
            for (int i = 0; i < 8; ++i) {
                float4 x = src[2 * i], y = src[2 * i + 1];
                uint4 v;
                v.x = pack2(x.x, x.y); v.y = pack2(x.z, x.w);
                v.z = pack2(y.x, y.y); v.w = pack2(y.z, y.w);
                dst[i] = v;
            }
        } else {
            const uint4 z = {0, 0, 0, 0};
#pragma unroll
            for (int i = 0; i < 8; ++i) dst[i] = z;
        }
        const uint4* bsrc = (const uint4*)(wk + (size_t)k * (COUT * CIN) + ar * CIN + ac);
        uint4* bdst = (uint4*)&ldsB[ar * 136 + ac];
#pragma unroll
        for (int i = 0; i < 8; ++i) bdst[i] = bsrc[i];
        __syncthreads();
#pragma unroll
        for (int kk = 0; kk < 4; ++kk) {
            bfrag8 a0 = *(const bfrag8*)(aP0 + kk * 32);
            bfrag8 a1 = *(const bfrag8*)(aP1 + kk * 32);
#pragma unroll
            for (int ct = 0; ct < 8; ++ct) {
                bfrag8 b = *(const bfrag8*)&ldsB[(ct * 16 + lr) * 136 + kk * 32 + lk * 8];
                acc0[ct] = __builtin_amdgcn_mfma_f32_16x16x32_bf16(a0, b, acc0[ct], 0, 0, 0);
                acc1[ct] = __builtin_amdgcn_mfma_f32_16x16x32_bf16(a1, b, acc1[ct], 0, 0, 0);
            }
        }
        __syncthreads();
    }
    const int rbase = m0 + w * 32 + lk * 4;
#pragma unroll
    for (int ct = 0; ct < 8; ++ct) {
#pragma unroll
        for (int r = 0; r < 4; ++r) {
            int row0 = rbase + r;
            if (row0 < N_PTS) out[(size_t)row0 * COUT + ct * 16 + lr] = acc0[ct][r];
            int row1 = row0 + 16;
            if (row1 < N_PTS) out[(size_t)row1 * COUT + ct * 16 + lr] = acc1[ct][r];
        }
    }
}

__global__ void naive_kernel(const float* __restrict__ data, const float* __restrict__ wgt,
                             const int* __restrict__ nbr, float* __restrict__ out) {
    int mm = blockIdx.x;
    int co = threadIdx.x;
    if (mm >= N_PTS) return;
    float acc = 0.f;
    for (int k = 0; k < NK; ++k) {
        int idx = nbr[mm * NK + k];
        if (idx < 0) continue;
        const float* d  = data + (size_t)idx * CIN;
        const float* wp = wgt + ((size_t)co * NK + k) * CIN;
        for (int ci = 0; ci < CIN; ++ci) acc += d[ci] * wp[ci];
    }
    out[(size_t)mm * COUT + co] = acc;
}

extern "C" void kernel_launch(void* const* d_in, const int* in_sizes, int n_in,
                              void* d_out, int out_size, void* d_ws, size_t ws_size,
                              hipStream_t stream) {
    const float* data = (const float*)d_in[0];
    const float* wgt  = (const float*)d_in[1];
    const int*   nbr  = (const int*)d_in[2];
    float*       out  = (float*)d_out;

    const size_t wk_bytes  = (size_t)NK * COUT * CIN * 2;           // 884,736 (16B aligned)
    const size_t dbf_bytes = (size_t)(N_PTS + 1) * CIN * 2;         // 38,400,256

    if (ws_size < wk_bytes) {
        naive_kernel<<<N_PTS, COUT, 0, stream>>>(data, wgt, nbr, out);
        return;
    }
    unsigned short* wk = (unsigned short*)d_ws;
    prep_weights_kernel<<<(NK * COUT * CIN / 4 + 255) / 256, 256, 0, stream>>>(
        wgt, wk, NK * COUT * CIN / 4);

    const int grid = (N_PTS + 127) / 128;
    if (ws_size >= wk_bytes + dbf_bytes) {
        unsigned short* dbf = (unsigned short*)((char*)d_ws + wk_bytes);
        cast_data_kernel<<<2048, 256, 0, stream>>>(data, dbf);
        octconv_pipe<<<grid, 256, 0, stream>>>(dbf, wk, nbr, out);
    } else {
        octconv_fp32<<<grid, 256, 0, stream>>>(data, wk, nbr, out);
    }
}

// Round 3
// 336.744 us; speedup vs baseline: 1.7264x; 1.7264x over previous
//
#include <hip/hip_runtime.h>

#define N_PTS 150000
#define NK 27
#define CIN 128
#define COUT 128

typedef __attribute__((ext_vector_type(8))) short bfrag8;   // 8 bf16
typedef __attribute__((ext_vector_type(4))) float facc4;    // 4 f32

__device__ inline unsigned short f2bf(float f) {
    unsigned u = __builtin_bit_cast(unsigned, f);
    u += 0x7FFFu + ((u >> 16) & 1u);            // RNE
    return (unsigned short)(u >> 16);
}
__device__ inline unsigned pack2(float a, float b) {
    return (unsigned)f2bf(a) | ((unsigned)f2bf(b) << 16);
}

__device__ inline void glds16(const void* g, void* l) {
    __builtin_amdgcn_global_load_lds(
        (const __attribute__((address_space(1))) void*)g,
        (__attribute__((address_space(3))) void*)l, 16, 0, 0);
}

// ---- prep: fp32 data -> bf16, plus one zeroed row at index N_PTS ----
__global__ void cast_data_kernel(const float* __restrict__ in,
                                 unsigned short* __restrict__ out) {
    const int n8_data = N_PTS * (CIN / 8);
    const int n8_all  = (N_PTS + 1) * (CIN / 8);
    int i = blockIdx.x * blockDim.x + threadIdx.x;
    int stride = gridDim.x * blockDim.x;
    for (; i < n8_all; i += stride) {
        uint4 v;
        if (i < n8_data) {
            const float4* p = (const float4*)(in + (size_t)i * 8);
            float4 x = p[0], y = p[1];
            v.x = pack2(x.x, x.y); v.y = pack2(x.z, x.w);
            v.z = pack2(y.x, y.y); v.w = pack2(y.z, y.w);
        } else {
            v.x = v.y = v.z = v.w = 0u;
        }
        *(uint4*)(out + (size_t)i * 8) = v;
    }
}

// ---- prep: W[co][k][ci] fp32 -> wks[k][co][unit] bf16, 16B-unit XOR-preswizzled ----
// stored unit u holds logical unit (u ^ (co&7)); read side applies same XOR.
__global__ void prep_weights_swz(const float* __restrict__ w,
                                 unsigned short* __restrict__ wks) {
    int i = blockIdx.x * blockDim.x + threadIdx.x;     // 16B unit id
    if (i >= NK * COUT * 16) return;
    int u  = i & 15;
    int co = (i >> 4) & 127;
    int k  = i >> 11;
    int us = u ^ (co & 7);
    const float4* src = (const float4*)(w + ((size_t)co * NK + k) * CIN + us * 8);
    float4 x = src[0], y = src[1];
    uint4 v;
    v.x = pack2(x.x, x.y); v.y = pack2(x.z, x.w);
    v.z = pack2(y.x, y.y); v.w = pack2(y.z, y.w);
    ((uint4*)wks)[i] = v;
}

// ================= main kernel =================
// Block: 128 rows x 128 couts, 4 waves, each wave (64 rows x 64 couts).
// A: gathered global->regs (double-buffered, zero-row trick).
// B: global_load_lds (pre-swizzled source) -> 2x32KB LDS double buffer.
// One __syncthreads per k; all prefetch issued before the MFMA phase.

#define PHASE(BUFR, AC, AN, IDXU, IDXL, KC)                                         \
  {                                                                                 \
    const int kp1_ = (KC) + 1;                                                      \
    if (kp1_ < NK) {                                                                \
      _Pragma("unroll")                                                             \
      for (int i_ = 0; i_ < 8; ++i_)                                                \
        glds16(wkb + (size_t)kp1_ * 32768 + chunk + i_ * 1024 + l * 16,             \
               (void*)(lbase + (1 - (BUFR)) * 32768 + chunk + i_ * 1024));          \
      _Pragma("unroll")                                                             \
      for (int rt_ = 0; rt_ < 4; ++rt_) {                                           \
        int e_ = IDXU[rt_] >= 0 ? IDXU[rt_] : N_PTS;                                \
        const uint4* p_ = (const uint4*)(dbf + (size_t)e_ * CIN + lk * 8);          \
        _Pragma("unroll")                                                           \
        for (int kk_ = 0; kk_ < 4; ++kk_) AN[rt_ * 4 + kk_] = p_[kk_ * 4];          \
      }                                                                             \
      const int k2_ = (kp1_ + 1 < NK) ? kp1_ + 1 : NK - 1;                          \
      _Pragma("unroll")                                                             \
      for (int rt_ = 0; rt_ < 4; ++rt_)                                             \
        IDXL[rt_] = valid[rt_] ? nbr[rown[rt_] * NK + k2_] : -1;                    \
    }                                                                               \
    _Pragma("unroll")                                                               \
    for (int kk_ = 0; kk_ < 4; ++kk_) {                                             \
      _Pragma("unroll")                                                             \
      for (int ct_ = 0; ct_ < 4; ++ct_) {                                           \
        const int brow_ = cbase + ct_ * 16 + lr;                                    \
        const int boff_ =                                                           \
            (BUFR) * 32768 + brow_ * 256 + (((kk_ * 4 + lk) ^ (brow_ & 7)) << 4);   \
        bfrag8 b_ = *(const bfrag8*)(lbase + boff_);                                \
        _Pragma("unroll")                                                           \
        for (int rt_ = 0; rt_ < 4; ++rt_)                                           \
          acc[rt_][ct_] = __builtin_amdgcn_mfma_f32_16x16x32_bf16(                  \
              __builtin_bit_cast(bfrag8, AC[rt_ * 4 + kk_]), b_, acc[rt_][ct_],     \
              0, 0, 0);                                                             \
      }                                                                             \
    }                                                                               \
    __syncthreads();                                                                \
  }

__global__ __launch_bounds__(256, 2)
void octconv_v3(const unsigned short* __restrict__ dbf,   // [N_PTS+1][128] bf16
                const unsigned short* __restrict__ wks,   // [27][128][16u] preswizzled
                const int* __restrict__ nbr,
                float* __restrict__ out) {
    __shared__ __align__(1024) unsigned char ldsB[2 * 32768];

    const int t  = threadIdx.x;
    const int w  = t >> 6;
    const int l  = t & 63;
    const int lr = l & 15;
    const int lk = l >> 4;
    const int wrow = w >> 1;
    const int wcol = w & 1;
    const int m0 = blockIdx.x * 128;
    const int rowbase = m0 + wrow * 64;
    const int cbase   = wcol * 64;

    int  rown[4];
    bool valid[4];
#pragma unroll
    for (int rt = 0; rt < 4; ++rt) {
        rown[rt]  = rowbase + rt * 16 + lr;
        valid[rt] = rown[rt] < N_PTS;
    }

    facc4 acc[4][4];
    const facc4 fz = {0.f, 0.f, 0.f, 0.f};
#pragma unroll
    for (int a = 0; a < 4; ++a)
#pragma unroll
        for (int b = 0; b < 4; ++b) acc[a][b] = fz;

    uint4 aX[16], aY[16];
    int   iX[4], iY[4];

    const char* wkb  = (const char*)wks;
    char*       lbase = (char*)ldsB;
    const int   chunk = w * 8192;

    // ---- prologue: B(0) glds, idx(0)->gather A(0), idx(1) ----
#pragma unroll
    for (int i = 0; i < 8; ++i)
        glds16(wkb + chunk + i * 1024 + l * 16, (void*)(lbase + chunk + i * 1024));
#pragma unroll
    for (int rt = 0; rt < 4; ++rt) iX[rt] = valid[rt] ? nbr[rown[rt] * NK + 0] : -1;
#pragma unroll
    for (int rt = 0; rt < 4; ++rt) {
        int e = iX[rt] >= 0 ? iX[rt] : N_PTS;
        const uint4* p = (const uint4*)(dbf + (size_t)e * CIN + lk * 8);
#pragma unroll
        for (int kk = 0; kk < 4; ++kk) aX[rt * 4 + kk] = p[kk * 4];
    }
#pragma unroll
    for (int rt = 0; rt < 4; ++rt) iY[rt] = valid[rt] ? nbr[rown[rt] * NK + 1] : -1;
    __syncthreads();

    // ---- 13 pairs (k = 0..25) + final k = 26 ----
    int k = 0;
#pragma unroll 1
    for (int kp = 0; kp < (NK - 1) / 2; ++kp, k += 2) {
        PHASE(0, aX, aY, iY, iX, k)
        PHASE(1, aY, aX, iX, iY, k + 1)
    }
    PHASE(0, aX, aY, iY, iX, NK - 1)

    // ---- epilogue: C/D col=lane&15, row=(lane>>4)*4+reg ----
#pragma unroll
    for (int rt = 0; rt < 4; ++rt) {
        const int r0 = rowbase + rt * 16 + lk * 4;
#pragma unroll
        for (int ct = 0; ct < 4; ++ct) {
#pragma unroll
            for (int r = 0; r < 4; ++r) {
                int row = r0 + r;
                if (row < N_PTS)
                    out[(size_t)row * COUT + cbase + ct * 16 + lr] = acc[rt][ct][r];
            }
        }
    }
}

// ---- emergency fallback ----
__global__ void naive_kernel(const float* __restrict__ data, const float* __restrict__ wgt,
                             const int* __restrict__ nbr, float* __restrict__ out) {
    int mm = blockIdx.x;
    int co = threadIdx.x;
    if (mm >= N_PTS) return;
    float acc = 0.f;
    for (int k = 0; k < NK; ++k) {
        int idx = nbr[mm * NK + k];
        if (idx < 0) continue;
        const float* d  = data + (size_t)idx * CIN;
        const float* wp = wgt + ((size_t)co * NK + k) * CIN;
        for (int ci = 0; ci < CIN; ++ci) acc += d[ci] * wp[ci];
    }
    out[(size_t)mm * COUT + co] = acc;
}

extern "C" void kernel_launch(void* const* d_in, const int* in_sizes, int n_in,
                              void* d_out, int out_size, void* d_ws, size_t ws_size,
                              hipStream_t stream) {
    const float* data = (const float*)d_in[0];
    const float* wgt  = (const float*)d_in[1];
    const int*   nbr  = (const int*)d_in[2];
    float*       out  = (float*)d_out;

    const size_t wk_bytes  = (size_t)NK * COUT * CIN * 2;      // 884,736
    const size_t dbf_bytes = (size_t)(N_PTS + 1) * CIN * 2;    // 38,400,256

    if (ws_size < wk_bytes + dbf_bytes) {
        naive_kernel<<<N_PTS, COUT, 0, stream>>>(data, wgt, nbr, out);
        return;
    }
    unsigned short* wks = (unsigned short*)d_ws;
    unsigned short* dbf = (unsigned short*)((char*)d_ws + wk_bytes);

    prep_weights_swz<<<(NK * COUT * 16 + 255) / 256, 256, 0, stream>>>(wgt, wks);
    cast_data_kernel<<<2048, 256, 0, stream>>>(data, dbf);

    const int grid = (N_PTS + 127) / 128;
    octconv_v3<<<grid, 256, 0, stream>>>(dbf, wks, nbr, out);
}

// Round 4
// 310.459 us; speedup vs baseline: 1.8726x; 1.0847x over previous
//
#include <hip/hip_runtime.h>

#define N_PTS 150000
#define NK 27
#define CIN 128
#define COUT 128

typedef __attribute__((ext_vector_type(8))) short bfrag8;   // 8 bf16
typedef __attribute__((ext_vector_type(4))) float facc4;    // 4 f32

__device__ inline unsigned short f2bf(float f) {
    unsigned u = __builtin_bit_cast(unsigned, f);
    u += 0x7FFFu + ((u >> 16) & 1u);            // RNE
    return (unsigned short)(u >> 16);
}
__device__ inline unsigned pack2(float a, float b) {
    return (unsigned)f2bf(a) | ((unsigned)f2bf(b) << 16);
}

__device__ inline void glds16(const void* g, void* l) {
    __builtin_amdgcn_global_load_lds(
        (const __attribute__((address_space(1))) void*)g,
        (__attribute__((address_space(3))) void*)l, 16, 0, 0);
}

// ---- prep: fp32 data -> bf16, plus one zeroed row at index N_PTS ----
__global__ void cast_data_kernel(const float* __restrict__ in,
                                 unsigned short* __restrict__ out) {
    const int n8_data = N_PTS * (CIN / 8);
    const int n8_all  = (N_PTS + 1) * (CIN / 8);
    int i = blockIdx.x * blockDim.x + threadIdx.x;
    int stride = gridDim.x * blockDim.x;
    for (; i < n8_all; i += stride) {
        uint4 v;
        if (i < n8_data) {
            const float4* p = (const float4*)(in + (size_t)i * 8);
            float4 x = p[0], y = p[1];
            v.x = pack2(x.x, x.y); v.y = pack2(x.z, x.w);
            v.z = pack2(y.x, y.y); v.w = pack2(y.z, y.w);
        } else {
            v.x = v.y = v.z = v.w = 0u;
        }
        *(uint4*)(out + (size_t)i * 8) = v;
    }
}

// ---- prep: W[co][k][ci] fp32 -> frag-linear wkf[k][h][ct][kk][lane] (16B units) ----
// unit(k,h,ct,kk,l) = bf16x8 of W[h*64+ct*16+(l&15)][k][kk*32+(l>>4)*8 .. +8]
__global__ void prep_weights_frag(const float* __restrict__ w,
                                  unsigned short* __restrict__ wkf) {
    int i = blockIdx.x * blockDim.x + threadIdx.x;
    if (i >= NK * 2 * 4 * 4 * 64) return;
    int l  = i & 63;
    int kk = (i >> 6) & 3;
    int ct = (i >> 8) & 3;
    int h  = (i >> 10) & 1;
    int k  = i >> 11;
    int co = h * 64 + ct * 16 + (l & 15);
    int ci = kk * 32 + (l >> 4) * 8;
    const float4* src = (const float4*)(w + ((size_t)co * NK + k) * CIN + ci);
    float4 x = src[0], y = src[1];
    uint4 v;
    v.x = pack2(x.x, x.y); v.y = pack2(x.z, x.w);
    v.z = pack2(y.x, y.y); v.w = pack2(y.z, y.w);
    ((uint4*)wkf)[i] = v;
}

// ================= main kernel =================
// Block: 128 rows x 128 couts, 4 waves, wave = 64 rows x 64 couts.
// A: gathered ONCE per block per k via global_load_lds into 2x32KB LDS dbuf,
//    XOR-swizzled via pre-swizzled per-lane global source (linear LDS dest).
// B: per-wave fragments loaded straight from L2 (frag-linear wkf) into regs,
//    double-buffered; no LDS, no barrier dependence.
// One __syncthreads per phase; all prefetch issued before the MFMA block.

#define PHASE(KC, BUF, BC, BN, IC, IN)                                              \
  {                                                                                 \
    if ((KC) + 1 < NK) {                                                            \
      _Pragma("unroll")                                                             \
      for (int j_ = 0; j_ < 8; ++j_) {                                              \
        int e_    = IC[j_] >= 0 ? IC[j_] : N_PTS;                                   \
        int slot_ = w * 32 + j_ * 4 + lg;                                           \
        const char* src_ = dbfb + (size_t)e_ * 256 + (((lu) ^ (slot_ & 7)) << 4);   \
        glds16(src_, ldsAb + (1 - (BUF)) * 32768 + slot_ * 256 + lu * 16);          \
      }                                                                             \
      _Pragma("unroll")                                                             \
      for (int j_ = 0; j_ < 16; ++j_)                                               \
        BN[j_] = pwkf[((size_t)((KC) + 1) * 32 + h16 + j_) * 64 + l];               \
      const int k2_ = ((KC) + 2 < NK) ? (KC) + 2 : NK - 1;                          \
      _Pragma("unroll")                                                             \
      for (int j_ = 0; j_ < 8; ++j_)                                                \
        IN[j_] = (rs + j_ * 4 < N_PTS) ? nbr[(size_t)(rs + j_ * 4) * NK + k2_] : -1;\
    }                                                                               \
    _Pragma("unroll")                                                               \
    for (int kk_ = 0; kk_ < 4; ++kk_) {                                             \
      uint4 a0_ = *(const uint4*)(ldsAb + (BUF) * 32768 + (abase + 0 * 16) * 256 +  \
                                  (((kk_ * 4 + lk) ^ (lr & 7)) << 4));              \
      uint4 a1_ = *(const uint4*)(ldsAb + (BUF) * 32768 + (abase + 1 * 16) * 256 +  \
                                  (((kk_ * 4 + lk) ^ (lr & 7)) << 4));              \
      uint4 a2_ = *(const uint4*)(ldsAb + (BUF) * 32768 + (abase + 2 * 16) * 256 +  \
                                  (((kk_ * 4 + lk) ^ (lr & 7)) << 4));              \
      uint4 a3_ = *(const uint4*)(ldsAb + (BUF) * 32768 + (abase + 3 * 16) * 256 +  \
                                  (((kk_ * 4 + lk) ^ (lr & 7)) << 4));              \
      _Pragma("unroll")                                                             \
      for (int ct_ = 0; ct_ < 4; ++ct_) {                                           \
        bfrag8 b_ = __builtin_bit_cast(bfrag8, BC[ct_ * 4 + kk_]);                  \
        acc[0][ct_] = __builtin_amdgcn_mfma_f32_16x16x32_bf16(                      \
            __builtin_bit_cast(bfrag8, a0_), b_, acc[0][ct_], 0, 0, 0);             \
        acc[1][ct_] = __builtin_amdgcn_mfma_f32_16x16x32_bf16(                      \
            __builtin_bit_cast(bfrag8, a1_), b_, acc[1][ct_], 0, 0, 0);             \
        acc[2][ct_] = __builtin_amdgcn_mfma_f32_16x16x32_bf16(                      \
            __builtin_bit_cast(bfrag8, a2_), b_, acc[2][ct_], 0, 0, 0);             \
        acc[3][ct_] = __builtin_amdgcn_mfma_f32_16x16x32_bf16(                      \
            __builtin_bit_cast(bfrag8, a3_), b_, acc[3][ct_], 0, 0, 0);             \
      }                                                                             \
    }                                                                               \
    __syncthreads();                                                                \
  }

__global__ __launch_bounds__(256, 2)
void octconv_v4(const unsigned short* __restrict__ dbf,   // [N_PTS+1][128] bf16
                const unsigned short* __restrict__ wkf,   // frag-linear weights
                const int* __restrict__ nbr,
                float* __restrict__ out) {
    __shared__ __align__(1024) unsigned char ldsA[2 * 32768];

    const int t    = threadIdx.x;
    const int w    = t >> 6;
    const int l    = t & 63;
    const int lr   = l & 15;
    const int lk   = l >> 4;
    const int lu   = l & 15;        // staging unit-in-row
    const int lg   = l >> 4;        // staging row-in-group
    const int wrow = w >> 1;
    const int h    = w & 1;
    const int h16  = h * 16;
    const int m0   = blockIdx.x * 128;
    const int rs   = m0 + w * 32 + lg;           // staging row for j-group 0
    const int abase = wrow * 64 + lr;            // LDS A row base for MFMA reads

    char* ldsAb = (char*)ldsA;
    const char* dbfb = (const char*)dbf;
    const uint4* pwkf = (const uint4*)wkf;

    facc4 acc[4][4];
    const facc4 fz = {0.f, 0.f, 0.f, 0.f};
#pragma unroll
    for (int a = 0; a < 4; ++a)
#pragma unroll
        for (int b = 0; b < 4; ++b) acc[a][b] = fz;

    uint4 BC[16], BN[16];
    int   IC[8], IN[8];

    // ---- prologue ----
    int I0[8];
#pragma unroll
    for (int j = 0; j < 8; ++j)
        I0[j] = (rs + j * 4 < N_PTS) ? nbr[(size_t)(rs + j * 4) * NK + 0] : -1;
#pragma unroll
    for (int j = 0; j < 16; ++j)
        BC[j] = pwkf[(size_t)(h16 + j) * 64 + l];
#pragma unroll
    for (int j = 0; j < 8; ++j) {
        int e    = I0[j] >= 0 ? I0[j] : N_PTS;
        int slot = w * 32 + j * 4 + lg;
        const char* src = dbfb + (size_t)e * 256 + (((lu) ^ (slot & 7)) << 4);
        glds16(src, ldsAb + slot * 256 + lu * 16);
    }
#pragma unroll
    for (int j = 0; j < 8; ++j)
        IC[j] = (rs + j * 4 < N_PTS) ? nbr[(size_t)(rs + j * 4) * NK + 1] : -1;
    __syncthreads();

    // ---- 13 phase-pairs (k = 0..25) + final k = 26 ----
    int k = 0;
#pragma unroll 1
    for (int kp = 0; kp < (NK - 1) / 2; ++kp, k += 2) {
        PHASE(k, 0, BC, BN, IC, IN)
        PHASE(k + 1, 1, BN, BC, IN, IC)
    }
    PHASE(26, 0, BC, BN, IC, IN)

    // ---- epilogue: C/D col=lane&15, row=(lane>>4)*4+reg ----
#pragma unroll
    for (int rt = 0; rt < 4; ++rt) {
        const int r0 = m0 + wrow * 64 + rt * 16 + lk * 4;
#pragma unroll
        for (int ct = 0; ct < 4; ++ct) {
#pragma unroll
            for (int r = 0; r < 4; ++r) {
                int row = r0 + r;
                if (row < N_PTS)
                    out[(size_t)row * COUT + h * 64 + ct * 16 + lr] = acc[rt][ct][r];
            }
        }
    }
}

// ---- emergency fallback ----
__global__ void naive_kernel(const float* __restrict__ data, const float* __restrict__ wgt,
                             const int* __restrict__ nbr, float* __restrict__ out) {
    int mm = blockIdx.x;
    int co = threadIdx.x;
    if (mm >= N_PTS) return;
    float acc = 0.f;
    for (int k = 0; k < NK; ++k) {
        int idx = nbr[mm * NK + k];
        if (idx < 0) continue;
        const float* d  = data + (size_t)idx * CIN;
        const float* wp = wgt + ((size_t)co * NK + k) * CIN;
        for (int ci = 0; ci < CIN; ++ci) acc += d[ci] * wp[ci];
    }
    out[(size_t)mm * COUT + co] = acc;
}

extern "C" void kernel_launch(void* const* d_in, const int* in_sizes, int n_in,
                              void* d_out, int out_size, void* d_ws, size_t ws_size,
                              hipStream_t stream) {
    const float* data = (const float*)d_in[0];
    const float* wgt  = (const float*)d_in[1];
    const int*   nbr  = (const int*)d_in[2];
    float*       out  = (float*)d_out;

    const size_t wk_bytes  = (size_t)NK * COUT * CIN * 2;      // 884,736
    const size_t dbf_bytes = (size_t)(N_PTS + 1) * CIN * 2;    // 38,400,256

    if (ws_size < wk_bytes + dbf_bytes) {
        naive_kernel<<<N_PTS, COUT, 0, stream>>>(data, wgt, nbr, out);
        return;
    }
    unsigned short* wkf = (unsigned short*)d_ws;
    unsigned short* dbf = (unsigned short*)((char*)d_ws + wk_bytes);

    prep_weights_frag<<<(NK * 2 * 4 * 4 * 64 + 255) / 256, 256, 0, stream>>>(wgt, wkf);
    cast_data_kernel<<<2048, 256, 0, stream>>>(data, dbf);

    const int grid = (N_PTS + 127) / 128;
    octconv_v4<<<grid, 256, 0, stream>>>(dbf, wkf, nbr, out);
}

// Round 6
// 203.216 us; speedup vs baseline: 2.8608x; 1.5277x over previous
//
#include <hip/hip_runtime.h>

#define N_PTS 150000
#define NK 27
#define CIN 128
#define COUT 128
#define BM 256
#define NBLK ((N_PTS + BM - 1) / BM)   // 586

typedef __attribute__((ext_vector_type(8))) short bfrag8;   // 8 bf16
typedef __attribute__((ext_vector_type(4))) float facc4;    // 4 f32

__device__ inline unsigned short f2bf(float f) {
    unsigned u = __builtin_bit_cast(unsigned, f);
    u += 0x7FFFu + ((u >> 16) & 1u);            // RNE
    return (unsigned short)(u >> 16);
}
__device__ inline unsigned pack2(float a, float b) {
    return (unsigned)f2bf(a) | ((unsigned)f2bf(b) << 16);
}
__device__ inline void glds16(const void* g, void* l) {
    __builtin_amdgcn_global_load_lds(
        (const __attribute__((address_space(1))) void*)g,
        (__attribute__((address_space(3))) void*)l, 16, 0, 0);
}
// end-of-phase: glds for next phase are the ONLY outstanding vmem -> exact wait
__device__ inline void phase_barrier() {
    __builtin_amdgcn_sched_barrier(0);
    asm volatile("s_waitcnt vmcnt(0)" ::: "memory");
    __builtin_amdgcn_s_barrier();
    __builtin_amdgcn_sched_barrier(0);
}

// ---- prep: fp32 data -> bf16, plus one zeroed row at index N_PTS ----
__global__ void cast_data_kernel(const float* __restrict__ in,
                                 unsigned short* __restrict__ out) {
    const int n8_data = N_PTS * (CIN / 8);
    const int n8_all  = (N_PTS + 1) * (CIN / 8);
    int i = blockIdx.x * blockDim.x + threadIdx.x;
    int stride = gridDim.x * blockDim.x;
    for (; i < n8_all; i += stride) {
        uint4 v;
        if (i < n8_data) {
            const float4* p = (const float4*)(in + (size_t)i * 8);
            float4 x = p[0], y = p[1];
            v.x = pack2(x.x, x.y); v.y = pack2(x.z, x.w);
            v.z = pack2(y.x, y.y); v.w = pack2(y.z, y.w);
        } else {
            v.x = v.y = v.z = v.w = 0u;
        }
        *(uint4*)(out + (size_t)i * 8) = v;
    }
}

// ---- prep: W[co][k][ci] -> wkh[k][h][co][bu] bf16 16B units, pre-swizzled bu^(co&7) ----
__global__ void prep_weights_h(const float* __restrict__ w,
                               unsigned short* __restrict__ wkh) {
    int i = blockIdx.x * blockDim.x + threadIdx.x;
    if (i >= NK * 2 * 128 * 8) return;
    int bu = i & 7, co = (i >> 3) & 127, h = (i >> 10) & 1, k = i >> 11;
    int ci = h * 64 + (bu ^ (co & 7)) * 8;
    const float4* src = (const float4*)(w + ((size_t)co * NK + k) * CIN + ci);
    float4 x = src[0], y = src[1];
    uint4 v;
    v.x = pack2(x.x, x.y); v.y = pack2(x.z, x.w);
    v.z = pack2(y.x, y.y); v.w = pack2(y.z, y.w);
    ((uint4*)wkh)[i] = v;
}

// ================= main kernel =================
// BM=256 x COUT=128, 1024 threads (16 waves, 4/SIMD), wave = 32 rows x 64 couts.
// 54 phases (27 k x 2 ci-halves, K=64 each). A: glds gather dedup'd per block,
// 2x32KB dbuf; B: glds staged once per phase, 2x16KB dbuf; idx: LDS slab.
// Loop vmem = 3 glds/thread/phase -> vmcnt(0)+barrier is an exact counted wait.
// NOTE swizzle discipline (rule #21): wkh is ALREADY pre-swizzled, so the B
// source read is LINEAR (bu = l&7); LDS then physically holds chunk^(co&7)
// and the MFMA read applies the XOR. (r5 bug: XOR applied on both sides.)

#define STAGE(K2H, HB, ADST0, ADST1, BDST)                                          \
  {                                                                                 \
    glds16(wkhB + (size_t)(K2H) * 16384 + bsrc_c, BDST);                            \
    int iv0 = *(const int*)(ldsI + i0base + ((K2H) >> 1) * 4);                      \
    int iv1 = *(const int*)(ldsI + i1base + ((K2H) >> 1) * 4);                      \
    size_t e0 = (r0ok && iv0 >= 0) ? (size_t)iv0 : (size_t)N_PTS;                   \
    size_t e1 = (r1ok && iv1 >= 0) ? (size_t)iv1 : (size_t)N_PTS;                   \
    glds16(dbfB + e0 * 256 + (HB) + aswz0, ADST0);                                  \
    glds16(dbfB + e1 * 256 + (HB) + aswz1, ADST1);                                  \
  }

#define MFMA_PHASE(ABUF, BBUF)                                                      \
  {                                                                                 \
    __builtin_amdgcn_s_setprio(1);                                                  \
    _Pragma("unroll")                                                               \
    for (int kk = 0; kk < 2; ++kk) {                                                \
      const int sw_ = (((kk * 4 + lk) ^ (lr & 7)) << 4);                            \
      bfrag8 a0 = *(const bfrag8*)((ABUF) + (wrow * 32 + lr) * 128 + sw_);          \
      bfrag8 a1 = *(const bfrag8*)((ABUF) + (wrow * 32 + 16 + lr) * 128 + sw_);     \
      _Pragma("unroll")                                                             \
      for (int ct = 0; ct < 4; ++ct) {                                              \
        bfrag8 b = *(const bfrag8*)((BBUF) + (h * 64 + ct * 16 + lr) * 128 + sw_);  \
        acc[0][ct] = __builtin_amdgcn_mfma_f32_16x16x32_bf16(a0, b, acc[0][ct],     \
                                                             0, 0, 0);              \
        acc[1][ct] = __builtin_amdgcn_mfma_f32_16x16x32_bf16(a1, b, acc[1][ct],     \
                                                             0, 0, 0);              \
      }                                                                             \
    }                                                                               \
    __builtin_amdgcn_s_setprio(0);                                                  \
  }

__global__ __launch_bounds__(1024, 4)
void octconv_v5(const unsigned short* __restrict__ dbf,   // [N_PTS+1][128] bf16
                const unsigned short* __restrict__ wkh,   // [27][2][128][8u] preswz
                const int* __restrict__ nbr,
                float* __restrict__ out) {
    __shared__ __align__(1024) unsigned char lds[98304 + 27648];  // A 64K | B 32K | idx 27K

    const int t = threadIdx.x;
    const int w = t >> 6, l = t & 63;
    const int lr = l & 15, lk = l >> 4;
    const int h = w & 1, wrow = w >> 1;
    const int m0 = blockIdx.x * BM;

    const int lu    = l & 7;
    const int slot0 = w * 16 + (l >> 3);
    const int slot1 = slot0 + 8;
    const bool r0ok = (m0 + slot0) < N_PTS;
    const bool r1ok = (m0 + slot1) < N_PTS;
    const int aswz0 = (lu ^ (slot0 & 7)) << 4;
    const int aswz1 = (lu ^ (slot1 & 7)) << 4;
    const int bco   = w * 8 + (l >> 3);
    const int bsrc_c = ((bco * 8 + (l & 7)) << 4);   // LINEAR: source is pre-swizzled
    const int i0base = slot0 * 108;
    const int i1base = slot1 * 108;

    const char* dbfB = (const char*)dbf;
    const char* wkhB = (const char*)wkh;
    char* ldsA0 = (char*)lds;
    char* ldsA1 = (char*)lds + 32768;
    char* ldsB0 = (char*)lds + 65536;
    char* ldsB1 = (char*)lds + 81920;
    char* ldsI  = (char*)lds + 98304;

    char* adst0_0 = ldsA0 + (w * 128 + l) * 16;
    char* adst0_1 = ldsA0 + (w * 128 + 64 + l) * 16;
    char* adst1_0 = ldsA1 + (w * 128 + l) * 16;
    char* adst1_1 = ldsA1 + (w * 128 + 64 + l) * 16;
    char* bdst0   = ldsB0 + t * 16;
    char* bdst1   = ldsB1 + t * 16;

    facc4 acc[2][4];
    const facc4 fz = {0.f, 0.f, 0.f, 0.f};
#pragma unroll
    for (int a = 0; a < 2; ++a)
#pragma unroll
        for (int b = 0; b < 4; ++b) acc[a][b] = fz;

    // ---- prologue 1: idx slab (guarded vs end of nbr) + B(0,0) ----
    {
        const char* nsrc = (const char*)nbr + (size_t)m0 * 108;
        const int rows_valid = (N_PTS - m0) < BM ? (N_PTS - m0) : BM;
        const int nlimit = rows_valid * 108;         // multiple of 16 at the tail block
        int o1 = t * 16;
        if (o1 < nlimit) glds16(nsrc + o1, ldsI + o1);
        int o2 = 16384 + t * 16;
        if (t < 704 && o2 < nlimit) glds16(nsrc + o2, ldsI + o2);
        glds16(wkhB + bsrc_c, bdst0);
    }
    phase_barrier();
    // ---- prologue 2: A(0, h=0) ----
    {
        int iv0 = *(const int*)(ldsI + i0base);
        int iv1 = *(const int*)(ldsI + i1base);
        size_t e0 = (r0ok && iv0 >= 0) ? (size_t)iv0 : (size_t)N_PTS;
        size_t e1 = (r1ok && iv1 >= 0) ? (size_t)iv1 : (size_t)N_PTS;
        glds16(dbfB + e0 * 256 + aswz0, adst0_0);
        glds16(dbfB + e1 * 256 + aswz1, adst0_1);
    }
    phase_barrier();

    // ---- 27 k-iterations x 2 phases ----
#pragma unroll 1
    for (int kp = 0; kp < NK; ++kp) {
        // even phase: compute (kp, h=0) from buf0; stage (kp, h=1) -> buf1
        STAGE(2 * kp + 1, 128, adst1_0, adst1_1, bdst1)
        MFMA_PHASE(ldsA0, ldsB0)
        phase_barrier();
        // odd phase: compute (kp, h=1) from buf1; stage (kp+1, h=0) -> buf0
        if (kp + 1 < NK) {
            STAGE(2 * kp + 2, 0, adst0_0, adst0_1, bdst0)
            MFMA_PHASE(ldsA1, ldsB1)
            phase_barrier();
        } else {
            MFMA_PHASE(ldsA1, ldsB1)
        }
    }

    // ---- epilogue: C/D col=lane&15, row=(lane>>4)*4+reg ----
#pragma unroll
    for (int rt = 0; rt < 2; ++rt) {
        const int r0 = m0 + wrow * 32 + rt * 16 + lk * 4;
#pragma unroll
        for (int ct = 0; ct < 4; ++ct) {
#pragma unroll
            for (int r = 0; r < 4; ++r) {
                int row = r0 + r;
                if (row < N_PTS)
                    out[(size_t)row * COUT + h * 64 + ct * 16 + lr] = acc[rt][ct][r];
            }
        }
    }
}

// ---- emergency fallback ----
__global__ void naive_kernel(const float* __restrict__ data, const float* __restrict__ wgt,
                             const int* __restrict__ nbr, float* __restrict__ out) {
    int mm = blockIdx.x;
    int co = threadIdx.x;
    if (mm >= N_PTS) return;
    float acc = 0.f;
    for (int k = 0; k < NK; ++k) {
        int idx = nbr[mm * NK + k];
        if (idx < 0) continue;
        const float* d  = data + (size_t)idx * CIN;
        const float* wp = wgt + ((size_t)co * NK + k) * CIN;
        for (int ci = 0; ci < CIN; ++ci) acc += d[ci] * wp[ci];
    }
    out[(size_t)mm * COUT + co] = acc;
}

extern "C" void kernel_launch(void* const* d_in, const int* in_sizes, int n_in,
                              void* d_out, int out_size, void* d_ws, size_t ws_size,
                              hipStream_t stream) {
    const float* data = (const float*)d_in[0];
    const float* wgt  = (const float*)d_in[1];
    const int*   nbr  = (const int*)d_in[2];
    float*       out  = (float*)d_out;

    const size_t wk_bytes  = (size_t)NK * 2 * 128 * 8 * 16;    // 884,736
    const size_t dbf_bytes = (size_t)(N_PTS + 1) * CIN * 2;    // 38,400,256

    if (ws_size < wk_bytes + dbf_bytes) {
        naive_kernel<<<N_PTS, COUT, 0, stream>>>(data, wgt, nbr, out);
        return;
    }
    unsigned short* wkh = (unsigned short*)d_ws;
    unsigned short* dbf = (unsigned short*)((char*)d_ws + wk_bytes);

    prep_weights_h<<<(NK * 2 * 128 * 8 + 255) / 256, 256, 0, stream>>>(wgt, wkh);
    cast_data_kernel<<<2048, 256, 0, stream>>>(data, dbf);

    octconv_v5<<<NBLK, 1024, 0, stream>>>(dbf, wkh, nbr, out);
}